// Round 1
// baseline (1083.790 us; speedup 1.0000x reference)
//
#include <hip/hip_runtime.h>
#include <math.h>

#define B_   16
#define HH   64
#define WW   64
#define CC   256
#define NN   4096   // HH*WW
#define MM   256    // (HH/4)*(WW/4)
#define NH   8
#define HD   32
#define SCALE_ 0.17677669529663687f  // 1/sqrt(32)

// ---------------- generic tiled GEMM: C[M,N] = A[M,K] @ B[K,N] + bias ----------------
// 64x64 block tile, 16 k-tile, 4x4 micro-tile per thread, 256 threads.
__global__ __launch_bounds__(256) void gemm_bias_kernel(
    const float* __restrict__ A, const float* __restrict__ B,
    const float* __restrict__ bias, float* __restrict__ C,
    int M, int N, int K)
{
  __shared__ float As[16][68];   // stored transposed As[k][m]; pad 68 -> conflict-free
  __shared__ float Bs[16][64];
  const int tid = threadIdx.x;
  const int tx = tid & 15, ty = tid >> 4;
  const int bm = blockIdx.y << 6, bn = blockIdx.x << 6;
  float acc[4][4] = {};
  for (int k0 = 0; k0 < K; k0 += 16) {
#pragma unroll
    for (int i = 0; i < 4; ++i) {
      int idx = tid + (i << 8);
      As[idx & 15][idx >> 4] = A[(size_t)(bm + (idx >> 4)) * K + (k0 + (idx & 15))];
    }
#pragma unroll
    for (int i = 0; i < 4; ++i) {
      int idx = tid + (i << 8);
      Bs[idx >> 6][idx & 63] = B[(size_t)(k0 + (idx >> 6)) * N + (bn + (idx & 63))];
    }
    __syncthreads();
#pragma unroll
    for (int kk = 0; kk < 16; ++kk) {
      float4 a = *(const float4*)&As[kk][ty << 2];
      float4 b = *(const float4*)&Bs[kk][tx << 2];
      acc[0][0] += a.x*b.x; acc[0][1] += a.x*b.y; acc[0][2] += a.x*b.z; acc[0][3] += a.x*b.w;
      acc[1][0] += a.y*b.x; acc[1][1] += a.y*b.y; acc[1][2] += a.y*b.z; acc[1][3] += a.y*b.w;
      acc[2][0] += a.z*b.x; acc[2][1] += a.z*b.y; acc[2][2] += a.z*b.z; acc[2][3] += a.z*b.w;
      acc[3][0] += a.w*b.x; acc[3][1] += a.w*b.y; acc[3][2] += a.w*b.z; acc[3][3] += a.w*b.w;
    }
    __syncthreads();
  }
#pragma unroll
  for (int i = 0; i < 4; ++i) {
    int row = bm + (ty << 2) + i;
    int col = bn + (tx << 2);
    float4 o;
    o.x = acc[i][0] + bias[col+0];
    o.y = acc[i][1] + bias[col+1];
    o.z = acc[i][2] + bias[col+2];
    o.w = acc[i][3] + bias[col+3];
    *(float4*)&C[(size_t)row * N + col] = o;
  }
}

// ------------- spatial-reduction conv (stride=kernel=4) as gathered GEMM -------------
// M = B_*MM = 4096 rows (b,oh,ow); N = 256 (co); K = 4096 (kh,kw,ci).
__global__ __launch_bounds__(256) void sr_conv_gemm_kernel(
    const float* __restrict__ x, const float* __restrict__ w,
    const float* __restrict__ bias, float* __restrict__ xs)
{
  __shared__ float As[16][68];
  __shared__ float Bs[16][64];
  const int tid = threadIdx.x;
  const int tx = tid & 15, ty = tid >> 4;
  const int bm = blockIdx.y << 6, bn = blockIdx.x << 6;
  float acc[4][4] = {};
  for (int k0 = 0; k0 < 4096; k0 += 16) {
#pragma unroll
    for (int i = 0; i < 4; ++i) {
      int idx = tid + (i << 8);
      int row = bm + (idx >> 4);
      int k   = k0 + (idx & 15);
      int b = row >> 8, mm = row & 255;
      int oh = mm >> 4, ow = mm & 15;
      int pos = k >> 8, ci = k & 255;
      int kh = pos >> 2, kw = pos & 3;
      As[idx & 15][idx >> 4] =
          x[((size_t)b * NN + (oh*4 + kh) * WW + (ow*4 + kw)) * CC + ci];
    }
#pragma unroll
    for (int i = 0; i < 4; ++i) {
      int idx = tid + (i << 8);
      Bs[idx >> 6][idx & 63] = w[(size_t)(k0 + (idx >> 6)) * CC + (bn + (idx & 63))];
    }
    __syncthreads();
#pragma unroll
    for (int kk = 0; kk < 16; ++kk) {
      float4 a = *(const float4*)&As[kk][ty << 2];
      float4 b = *(const float4*)&Bs[kk][tx << 2];
      acc[0][0] += a.x*b.x; acc[0][1] += a.x*b.y; acc[0][2] += a.x*b.z; acc[0][3] += a.x*b.w;
      acc[1][0] += a.y*b.x; acc[1][1] += a.y*b.y; acc[1][2] += a.y*b.z; acc[1][3] += a.y*b.w;
      acc[2][0] += a.z*b.x; acc[2][1] += a.z*b.y; acc[2][2] += a.z*b.z; acc[2][3] += a.z*b.w;
      acc[3][0] += a.w*b.x; acc[3][1] += a.w*b.y; acc[3][2] += a.w*b.z; acc[3][3] += a.w*b.w;
    }
    __syncthreads();
  }
#pragma unroll
  for (int i = 0; i < 4; ++i) {
    int row = bm + (ty << 2) + i;
    int col = bn + (tx << 2);
    float4 o;
    o.x = acc[i][0] + bias[col+0];
    o.y = acc[i][1] + bias[col+1];
    o.z = acc[i][2] + bias[col+2];
    o.w = acc[i][3] + bias[col+3];
    *(float4*)&xs[(size_t)row * CC + col] = o;
  }
}

// ---------------- LayerNorm over last dim (C=256), one block per row ----------------
__global__ __launch_bounds__(256) void ln_kernel(
    float* __restrict__ xs, const float* __restrict__ g, const float* __restrict__ bta)
{
  const int row = blockIdx.x, t = threadIdx.x;
  float v = xs[(size_t)row * CC + t];
  float s = v, s2 = v * v;
#pragma unroll
  for (int off = 32; off; off >>= 1) {
    s  += __shfl_xor(s,  off, 64);
    s2 += __shfl_xor(s2, off, 64);
  }
  __shared__ float red[8];
  const int w = t >> 6, lane = t & 63;
  if (lane == 0) { red[w] = s; red[4 + w] = s2; }
  __syncthreads();
  float ts  = red[0] + red[1] + red[2] + red[3];
  float ts2 = red[4] + red[5] + red[6] + red[7];
  float mu  = ts * (1.0f / 256.0f);
  float var = ts2 * (1.0f / 256.0f) - mu * mu;
  float o = (v - mu) * rsqrtf(var + 1e-6f) * g[t] + bta[t];
  xs[(size_t)row * CC + t] = o;
}

// ---------------- fused attention: 32 q-rows per block, one (b,h) slice ----------------
// LDS: Qs[32][36] + union{ K[256][36] ; P/S[32][260] }  = 41.5 KB -> 3 blocks/CU
__global__ __launch_bounds__(256) void attn_kernel(
    float* __restrict__ q, const float* __restrict__ kv)
{
  __shared__ float Qs[32][36];
  __shared__ float SK[9216];               // 36 KB union region
  float (*Ks)[36]  = (float(*)[36])SK;     // K tile   [256][36]
  float (*S)[260]  = (float(*)[260])SK;    // scores/P [32][260]
  const int tid = threadIdx.x;
  const int bid = blockIdx.x;
  const int nt = bid & 127;
  const int h  = (bid >> 7) & 7;
  const int b  = bid >> 10;
  const int n0 = nt << 5;

  // load Q tile (pre-scaled)
#pragma unroll
  for (int i = 0; i < 4; ++i) {
    int idx = tid + (i << 8);
    int r = idx >> 5, k = idx & 31;
    Qs[r][k] = q[((size_t)(b * NN + n0 + r)) * CC + h * HD + k] * SCALE_;
  }
  // load K tile
#pragma unroll
  for (int i = 0; i < 32; ++i) {
    int idx = tid + (i << 8);
    int m = idx >> 5, d = idx & 31;
    Ks[m][d] = kv[((size_t)(b * MM + m)) * (2 * CC) + h * HD + d];
  }
  __syncthreads();

  // phase 1: S = (Q*scale) @ K^T   (4 rows x 8 strided cols per thread)
  const int r0 = (tid >> 5) << 2;   // 0,4,...,28
  const int c0 = tid & 31;          // cols c0 + 32*j
  float acc[4][8];
#pragma unroll
  for (int i = 0; i < 4; ++i)
#pragma unroll
    for (int j = 0; j < 8; ++j) acc[i][j] = 0.f;
#pragma unroll
  for (int k4 = 0; k4 < 8; ++k4) {
    float4 a0 = *(const float4*)&Qs[r0+0][k4 << 2];
    float4 a1 = *(const float4*)&Qs[r0+1][k4 << 2];
    float4 a2 = *(const float4*)&Qs[r0+2][k4 << 2];
    float4 a3 = *(const float4*)&Qs[r0+3][k4 << 2];
#pragma unroll
    for (int j = 0; j < 8; ++j) {
      float4 kk = *(const float4*)&Ks[c0 + (j << 5)][k4 << 2];
      acc[0][j] += a0.x*kk.x + a0.y*kk.y + a0.z*kk.z + a0.w*kk.w;
      acc[1][j] += a1.x*kk.x + a1.y*kk.y + a1.z*kk.z + a1.w*kk.w;
      acc[2][j] += a2.x*kk.x + a2.y*kk.y + a2.z*kk.z + a2.w*kk.w;
      acc[3][j] += a3.x*kk.x + a3.y*kk.y + a3.z*kk.z + a3.w*kk.w;
    }
  }
  __syncthreads();   // all K reads done before overwriting the union with S
#pragma unroll
  for (int i = 0; i < 4; ++i)
#pragma unroll
    for (int j = 0; j < 8; ++j)
      S[r0 + i][c0 + (j << 5)] = acc[i][j];
  __syncthreads();

  // phase 2: row softmax (each wave owns 8 rows; 64 lanes x 4 cols)
  {
    const int w = tid >> 6, lane = tid & 63;
#pragma unroll
    for (int rr = 0; rr < 8; ++rr) {
      int r = (w << 3) + rr;
      float4 v = *(const float4*)&S[r][lane << 2];
      float mx = fmaxf(fmaxf(v.x, v.y), fmaxf(v.z, v.w));
#pragma unroll
      for (int off = 32; off; off >>= 1) mx = fmaxf(mx, __shfl_xor(mx, off, 64));
      float e0 = __expf(v.x - mx), e1 = __expf(v.y - mx),
            e2 = __expf(v.z - mx), e3 = __expf(v.w - mx);
      float sm = e0 + e1 + e2 + e3;
#pragma unroll
      for (int off = 32; off; off >>= 1) sm += __shfl_xor(sm, off, 64);
      float inv = 1.0f / sm;
      float4 p = make_float4(e0 * inv, e1 * inv, e2 * inv, e3 * inv);
      *(float4*)&S[r][lane << 2] = p;
    }
  }
  __syncthreads();

  // phase 3: O = P @ V  (V streamed from global/L1), write back in place over q
  {
    const int r  = tid >> 3;
    const int d0 = (tid & 7) << 2;
    const float* vbase = kv + (size_t)(b * MM) * (2 * CC) + CC + h * HD + d0;
    float4 o = make_float4(0.f, 0.f, 0.f, 0.f);
    for (int m4 = 0; m4 < 64; ++m4) {
      float4 p  = *(const float4*)&S[r][m4 << 2];
      float4 v0 = *(const float4*)(vbase + (size_t)((m4 << 2) + 0) * (2 * CC));
      float4 v1 = *(const float4*)(vbase + (size_t)((m4 << 2) + 1) * (2 * CC));
      float4 v2 = *(const float4*)(vbase + (size_t)((m4 << 2) + 2) * (2 * CC));
      float4 v3 = *(const float4*)(vbase + (size_t)((m4 << 2) + 3) * (2 * CC));
      o.x += p.x*v0.x + p.y*v1.x + p.z*v2.x + p.w*v3.x;
      o.y += p.x*v0.y + p.y*v1.y + p.z*v2.y + p.w*v3.y;
      o.z += p.x*v0.z + p.y*v1.z + p.z*v2.z + p.w*v3.z;
      o.w += p.x*v0.w + p.y*v1.w + p.z*v2.w + p.w*v3.w;
    }
    *(float4*)&q[((size_t)(b * NN + n0 + r)) * CC + h * HD + d0] = o;
  }
}

extern "C" void kernel_launch(void* const* d_in, const int* in_sizes, int n_in,
                              void* d_out, int out_size, void* d_ws, size_t ws_size,
                              hipStream_t stream) {
  const float* x      = (const float*)d_in[0];
  const float* q_w    = (const float*)d_in[1];
  const float* q_b    = (const float*)d_in[2];
  const float* kv_w   = (const float*)d_in[3];
  const float* kv_b   = (const float*)d_in[4];
  const float* sr_w   = (const float*)d_in[5];
  const float* sr_b   = (const float*)d_in[6];
  const float* norm_g = (const float*)d_in[7];
  const float* norm_b = (const float*)d_in[8];
  const float* proj_w = (const float*)d_in[9];
  const float* proj_b = (const float*)d_in[10];
  float* out = (float*)d_out;

  float* qbuf  = (float*)d_ws;                    // B*N*C          = 16,777,216 f
  float* xsbuf = qbuf + (size_t)B_ * NN * CC;     // B*M*C          =  1,048,576 f
  float* kvbuf = xsbuf + (size_t)B_ * MM * CC;    // B*M*2C         =  2,097,152 f

  dim3 blk(256);

  // 1) q = x @ q_w + q_b              [65536,256] @ [256,256]
  gemm_bias_kernel<<<dim3(CC / 64, (B_ * NN) / 64), blk, 0, stream>>>(
      x, q_w, q_b, qbuf, B_ * NN, CC, CC);

  // 2) xs = stride-4 conv (patch GEMM)   [4096,4096] x [4096,256]
  sr_conv_gemm_kernel<<<dim3(CC / 64, (B_ * MM) / 64), blk, 0, stream>>>(
      x, sr_w, sr_b, xsbuf);

  // 3) LayerNorm rows of xs
  ln_kernel<<<B_ * MM, blk, 0, stream>>>(xsbuf, norm_g, norm_b);

  // 4) kv = xs @ kv_w + kv_b          [4096,256] @ [256,512]
  gemm_bias_kernel<<<dim3((2 * CC) / 64, (B_ * MM) / 64), blk, 0, stream>>>(
      xsbuf, kv_w, kv_b, kvbuf, B_ * MM, 2 * CC, CC);

  // 5) attention, in place over qbuf   (16*8*128 blocks)
  attn_kernel<<<B_ * NH * (NN / 32), blk, 0, stream>>>(qbuf, kvbuf);

  // 6) out = attn_out @ proj_w + proj_b
  gemm_bias_kernel<<<dim3(CC / 64, (B_ * NN) / 64), blk, 0, stream>>>(
      qbuf, proj_w, proj_b, out, B_ * NN, CC, CC);
}

// Round 2
// 661.697 us; speedup vs baseline: 1.6379x; 1.6379x over previous
//
#include <hip/hip_runtime.h>
#include <math.h>

#define B_   16
#define HH   64
#define WW   64
#define CC   256
#define NN   4096   // HH*WW
#define MM   256    // (HH/4)*(WW/4)
#define NH   8
#define HD   32
#define SCALE_ 0.17677669529663687f  // 1/sqrt(32)

typedef float fx4 __attribute__((ext_vector_type(4)));
typedef short sx4 __attribute__((ext_vector_type(4)));
typedef short sx8 __attribute__((ext_vector_type(8)));

__device__ inline short f2bf(float f) {
  unsigned u = __builtin_bit_cast(unsigned, f);
  u += 0x7FFFu + ((u >> 16) & 1u);   // RNE; inputs are finite/sane
  return (short)(u >> 16);
}

// ---------------- generic tiled GEMM: C[M,N] = A[M,K] @ B[K,N] + bias ----------------
__global__ __launch_bounds__(256) void gemm_bias_kernel(
    const float* __restrict__ A, const float* __restrict__ B,
    const float* __restrict__ bias, float* __restrict__ C,
    int M, int N, int K)
{
  __shared__ float As[16][68];
  __shared__ float Bs[16][64];
  const int tid = threadIdx.x;
  const int tx = tid & 15, ty = tid >> 4;
  const int bm = blockIdx.y << 6, bn = blockIdx.x << 6;
  float acc[4][4] = {};
  for (int k0 = 0; k0 < K; k0 += 16) {
#pragma unroll
    for (int i = 0; i < 4; ++i) {
      int idx = tid + (i << 8);
      As[idx & 15][idx >> 4] = A[(size_t)(bm + (idx >> 4)) * K + (k0 + (idx & 15))];
    }
#pragma unroll
    for (int i = 0; i < 4; ++i) {
      int idx = tid + (i << 8);
      Bs[idx >> 6][idx & 63] = B[(size_t)(k0 + (idx >> 6)) * N + (bn + (idx & 63))];
    }
    __syncthreads();
#pragma unroll
    for (int kk = 0; kk < 16; ++kk) {
      float4 a = *(const float4*)&As[kk][ty << 2];
      float4 b = *(const float4*)&Bs[kk][tx << 2];
      acc[0][0] += a.x*b.x; acc[0][1] += a.x*b.y; acc[0][2] += a.x*b.z; acc[0][3] += a.x*b.w;
      acc[1][0] += a.y*b.x; acc[1][1] += a.y*b.y; acc[1][2] += a.y*b.z; acc[1][3] += a.y*b.w;
      acc[2][0] += a.z*b.x; acc[2][1] += a.z*b.y; acc[2][2] += a.z*b.z; acc[2][3] += a.z*b.w;
      acc[3][0] += a.w*b.x; acc[3][1] += a.w*b.y; acc[3][2] += a.w*b.z; acc[3][3] += a.w*b.w;
    }
    __syncthreads();
  }
#pragma unroll
  for (int i = 0; i < 4; ++i) {
    int row = bm + (ty << 2) + i;
    int col = bn + (tx << 2);
    float4 o;
    o.x = acc[i][0] + bias[col+0];
    o.y = acc[i][1] + bias[col+1];
    o.z = acc[i][2] + bias[col+2];
    o.w = acc[i][3] + bias[col+3];
    *(float4*)&C[(size_t)row * N + col] = o;
  }
}

// ------------- spatial-reduction conv (stride=kernel=4) as gathered GEMM -------------
__global__ __launch_bounds__(256) void sr_conv_gemm_kernel(
    const float* __restrict__ x, const float* __restrict__ w,
    const float* __restrict__ bias, float* __restrict__ xs)
{
  __shared__ float As[16][68];
  __shared__ float Bs[16][64];
  const int tid = threadIdx.x;
  const int tx = tid & 15, ty = tid >> 4;
  const int bm = blockIdx.y << 6, bn = blockIdx.x << 6;
  float acc[4][4] = {};
  for (int k0 = 0; k0 < 4096; k0 += 16) {
#pragma unroll
    for (int i = 0; i < 4; ++i) {
      int idx = tid + (i << 8);
      int row = bm + (idx >> 4);
      int k   = k0 + (idx & 15);
      int b = row >> 8, mm = row & 255;
      int oh = mm >> 4, ow = mm & 15;
      int pos = k >> 8, ci = k & 255;
      int kh = pos >> 2, kw = pos & 3;
      As[idx & 15][idx >> 4] =
          x[((size_t)b * NN + (oh*4 + kh) * WW + (ow*4 + kw)) * CC + ci];
    }
#pragma unroll
    for (int i = 0; i < 4; ++i) {
      int idx = tid + (i << 8);
      Bs[idx >> 6][idx & 63] = w[(size_t)(k0 + (idx >> 6)) * CC + (bn + (idx & 63))];
    }
    __syncthreads();
#pragma unroll
    for (int kk = 0; kk < 16; ++kk) {
      float4 a = *(const float4*)&As[kk][ty << 2];
      float4 b = *(const float4*)&Bs[kk][tx << 2];
      acc[0][0] += a.x*b.x; acc[0][1] += a.x*b.y; acc[0][2] += a.x*b.z; acc[0][3] += a.x*b.w;
      acc[1][0] += a.y*b.x; acc[1][1] += a.y*b.y; acc[1][2] += a.y*b.z; acc[1][3] += a.y*b.w;
      acc[2][0] += a.z*b.x; acc[2][1] += a.z*b.y; acc[2][2] += a.z*b.z; acc[2][3] += a.z*b.w;
      acc[3][0] += a.w*b.x; acc[3][1] += a.w*b.y; acc[3][2] += a.w*b.z; acc[3][3] += a.w*b.w;
    }
    __syncthreads();
  }
#pragma unroll
  for (int i = 0; i < 4; ++i) {
    int row = bm + (ty << 2) + i;
    int col = bn + (tx << 2);
    float4 o;
    o.x = acc[i][0] + bias[col+0];
    o.y = acc[i][1] + bias[col+1];
    o.z = acc[i][2] + bias[col+2];
    o.w = acc[i][3] + bias[col+3];
    *(float4*)&xs[(size_t)row * CC + col] = o;
  }
}

// ---------------- LayerNorm over last dim (C=256), one block per row ----------------
__global__ __launch_bounds__(256) void ln_kernel(
    float* __restrict__ xs, const float* __restrict__ g, const float* __restrict__ bta)
{
  const int row = blockIdx.x, t = threadIdx.x;
  float v = xs[(size_t)row * CC + t];
  float s = v, s2 = v * v;
#pragma unroll
  for (int off = 32; off; off >>= 1) {
    s  += __shfl_xor(s,  off, 64);
    s2 += __shfl_xor(s2, off, 64);
  }
  __shared__ float red[8];
  const int w = t >> 6, lane = t & 63;
  if (lane == 0) { red[w] = s; red[4 + w] = s2; }
  __syncthreads();
  float ts  = red[0] + red[1] + red[2] + red[3];
  float ts2 = red[4] + red[5] + red[6] + red[7];
  float mu  = ts * (1.0f / 256.0f);
  float var = ts2 * (1.0f / 256.0f) - mu * mu;
  float o = (v - mu) * rsqrtf(var + 1e-6f) * g[t] + bta[t];
  xs[(size_t)row * CC + t] = o;
}

// ---------------- MFMA attention: 32 q-rows / block, one (b,h), 4 waves ----------------
// wave w: row-group rg=w>>1 (16 rows), col-half ch=w&1 (128 of 256 k-cols for S,
// 16 of 32 d-cols for O). K: bf16 [256][36]; V^T: bf16 [32][264]; P: bf16 [32][264].
__global__ __launch_bounds__(256) void attn_mfma_kernel(
    float* __restrict__ q, const float* __restrict__ kv)
{
  __shared__ short Ks[256*36];
  __shared__ short Vt[32*264];
  __shared__ short Ps[32*264];
  __shared__ float redm[4][16];
  __shared__ float reds[4][16];

  const int tid = threadIdx.x;
  const int bid = blockIdx.x;
  const int nt = bid & 127, h = (bid >> 7) & 7, b = bid >> 10;
  const int n0 = nt << 5;
  const size_t kvbase = (size_t)(b * MM) * (2*CC) + h * HD;

  // ---- stage K (row-major) and V (transposed) as bf16 ----
  {
    const int d0 = (tid & 7) << 2;
    const int mb = tid >> 3;
#pragma unroll
    for (int it = 0; it < 8; ++it) {
      int m = mb + (it << 5);
      float4 kf = *(const float4*)&kv[kvbase + (size_t)m*(2*CC) + d0];
      sx4 kk = { f2bf(kf.x), f2bf(kf.y), f2bf(kf.z), f2bf(kf.w) };
      *(sx4*)&Ks[m*36 + d0] = kk;
      float4 vf = *(const float4*)&kv[kvbase + (size_t)m*(2*CC) + CC + d0];
      Vt[(d0+0)*264 + m] = f2bf(vf.x);
      Vt[(d0+1)*264 + m] = f2bf(vf.y);
      Vt[(d0+2)*264 + m] = f2bf(vf.z);
      Vt[(d0+3)*264 + m] = f2bf(vf.w);
    }
  }

  const int w  = tid >> 6, l = tid & 63;
  const int g  = l >> 4,  c = l & 15;
  const int rg = w >> 1,  ch = w & 1;

  // ---- Q A-fragment straight from global (row = c, k = 8g+j), scale folded ----
  sx8 aq;
  {
    const float* qp = q + ((size_t)(b*NN + n0 + rg*16 + c))*CC + h*HD + (g<<3);
    float4 qa = *(const float4*)qp;
    float4 qb = *(const float4*)(qp + 4);
    aq[0]=f2bf(qa.x*SCALE_); aq[1]=f2bf(qa.y*SCALE_); aq[2]=f2bf(qa.z*SCALE_); aq[3]=f2bf(qa.w*SCALE_);
    aq[4]=f2bf(qb.x*SCALE_); aq[5]=f2bf(qb.y*SCALE_); aq[6]=f2bf(qb.z*SCALE_); aq[7]=f2bf(qb.w*SCALE_);
  }
  __syncthreads();

  // ---- S = Q K^T over this wave's 8 col-tiles (K-dim = 32 = one MFMA) ----
  fx4 acc[8];
#pragma unroll
  for (int j = 0; j < 8; ++j) {
    int t   = (ch << 3) + j;
    int row = t*16 + c;
    sx4 b0 = *(const sx4*)&Ks[row*36 + (g<<3)];
    sx4 b1 = *(const sx4*)&Ks[row*36 + (g<<3) + 4];
    sx8 bk = { b0[0],b0[1],b0[2],b0[3], b1[0],b1[1],b1[2],b1[3] };
    fx4 z = {0.f,0.f,0.f,0.f};
    acc[j] = __builtin_amdgcn_mfma_f32_16x16x32_bf16(aq, bk, z, 0, 0, 0);
  }

  // ---- softmax: partial max over 128 cols, combine with partner wave ----
  float mx[4], sm[4];
#pragma unroll
  for (int i = 0; i < 4; ++i) {
    float m0 = acc[0][i];
#pragma unroll
    for (int j = 1; j < 8; ++j) m0 = fmaxf(m0, acc[j][i]);
    m0 = fmaxf(m0, __shfl_xor(m0, 1, 64));
    m0 = fmaxf(m0, __shfl_xor(m0, 2, 64));
    m0 = fmaxf(m0, __shfl_xor(m0, 4, 64));
    m0 = fmaxf(m0, __shfl_xor(m0, 8, 64));
    mx[i] = m0;
  }
  if (c == 0) {
#pragma unroll
    for (int i = 0; i < 4; ++i) redm[w][(g<<2)+i] = mx[i];
  }
  __syncthreads();

#pragma unroll
  for (int i = 0; i < 4; ++i) {
    float M  = fmaxf(mx[i], redm[w^1][(g<<2)+i]);
    float s0 = 0.f;
#pragma unroll
    for (int j = 0; j < 8; ++j) { float p = __expf(acc[j][i] - M); acc[j][i] = p; s0 += p; }
    s0 += __shfl_xor(s0, 1, 64);
    s0 += __shfl_xor(s0, 2, 64);
    s0 += __shfl_xor(s0, 4, 64);
    s0 += __shfl_xor(s0, 8, 64);
    sm[i] = s0;
  }
  if (c == 0) {
#pragma unroll
    for (int i = 0; i < 4; ++i) reds[w][(g<<2)+i] = sm[i];
  }
  // un-normalized P -> LDS bf16 (normalize O at the end: 32 divs/row not 256)
#pragma unroll
  for (int j = 0; j < 8; ++j) {
#pragma unroll
    for (int i = 0; i < 4; ++i)
      Ps[(rg*16 + (g<<2)+i)*264 + (ch<<7) + j*16 + c] = f2bf(acc[j][i]);
  }
  __syncthreads();

  // ---- O = P V : 8 k-steps of 32, wave owns [16 rows][16 d-cols] ----
  fx4 o = {0.f,0.f,0.f,0.f};
#pragma unroll
  for (int s = 0; s < 8; ++s) {
    sx8 ap = *(const sx8*)&Ps[(rg*16 + c)*264 + (s<<5) + (g<<3)];
    sx8 bv = *(const sx8*)&Vt[(ch*16 + c)*264 + (s<<5) + (g<<3)];
    o = __builtin_amdgcn_mfma_f32_16x16x32_bf16(ap, bv, o, 0, 0, 0);
  }
#pragma unroll
  for (int i = 0; i < 4; ++i) {
    float tot = reds[w][(g<<2)+i] + reds[w^1][(g<<2)+i];
    float ov  = o[i] / tot;
    q[((size_t)(b*NN + n0 + rg*16 + (g<<2)+i))*CC + h*HD + ch*16 + c] = ov;
  }
}

extern "C" void kernel_launch(void* const* d_in, const int* in_sizes, int n_in,
                              void* d_out, int out_size, void* d_ws, size_t ws_size,
                              hipStream_t stream) {
  const float* x      = (const float*)d_in[0];
  const float* q_w    = (const float*)d_in[1];
  const float* q_b    = (const float*)d_in[2];
  const float* kv_w   = (const float*)d_in[3];
  const float* kv_b   = (const float*)d_in[4];
  const float* sr_w   = (const float*)d_in[5];
  const float* sr_b   = (const float*)d_in[6];
  const float* norm_g = (const float*)d_in[7];
  const float* norm_b = (const float*)d_in[8];
  const float* proj_w = (const float*)d_in[9];
  const float* proj_b = (const float*)d_in[10];
  float* out = (float*)d_out;

  float* qbuf  = (float*)d_ws;                    // B*N*C
  float* xsbuf = qbuf + (size_t)B_ * NN * CC;     // B*M*C
  float* kvbuf = xsbuf + (size_t)B_ * MM * CC;    // B*M*2C

  dim3 blk(256);

  gemm_bias_kernel<<<dim3(CC / 64, (B_ * NN) / 64), blk, 0, stream>>>(
      x, q_w, q_b, qbuf, B_ * NN, CC, CC);

  sr_conv_gemm_kernel<<<dim3(CC / 64, (B_ * MM) / 64), blk, 0, stream>>>(
      x, sr_w, sr_b, xsbuf);

  ln_kernel<<<B_ * MM, blk, 0, stream>>>(xsbuf, norm_g, norm_b);

  gemm_bias_kernel<<<dim3((2 * CC) / 64, (B_ * MM) / 64), blk, 0, stream>>>(
      xsbuf, kv_w, kv_b, kvbuf, B_ * MM, 2 * CC, CC);

  attn_mfma_kernel<<<B_ * NH * (NN / 32), blk, 0, stream>>>(qbuf, kvbuf);

  gemm_bias_kernel<<<dim3(CC / 64, (B_ * NN) / 64), blk, 0, stream>>>(
      qbuf, proj_w, proj_b, out, B_ * NN, CC, CC);
}

// Round 3
// 355.871 us; speedup vs baseline: 3.0455x; 1.8594x over previous
//
#include <hip/hip_runtime.h>
#include <math.h>

#define B_   16
#define CC   256
#define NN   4096   // 64*64
#define MM   256    // 16*16
#define NH   8
#define HD   32
#define SCALE_ 0.17677669529663687f  // 1/sqrt(32)

typedef float fx4 __attribute__((ext_vector_type(4)));
typedef short sx4 __attribute__((ext_vector_type(4)));
typedef short sx8 __attribute__((ext_vector_type(8)));

__device__ inline short f2bf(float f) {
  unsigned u = __builtin_bit_cast(unsigned, f);
  u += 0x7FFFu + ((u >> 16) & 1u);   // RNE
  return (short)(u >> 16);
}
__device__ inline float bf2f(short s) {
  unsigned u = ((unsigned)(unsigned short)s) << 16;
  return __builtin_bit_cast(float, u);
}

// ---------- weight transpose + bf16 split: W[K][N] f32 -> Th/Tl[N][K] bf16 ----------
__global__ __launch_bounds__(256) void wsplit_kernel(
    const float* __restrict__ W, short* __restrict__ Th, short* __restrict__ Tl,
    int K, int N)
{
  __shared__ float Tile[64][65];
  const int t = threadIdx.x;
  const int k0 = blockIdx.y << 6, n0 = blockIdx.x << 6;
#pragma unroll
  for (int i = 0; i < 4; ++i) {
    int idx = t + (i << 8);
    int k = idx >> 4, n4 = (idx & 15) << 2;
    float4 v = *(const float4*)&W[(size_t)(k0 + k) * N + n0 + n4];
    Tile[k][n4 + 0] = v.x; Tile[k][n4 + 1] = v.y;
    Tile[k][n4 + 2] = v.z; Tile[k][n4 + 3] = v.w;
  }
  __syncthreads();
#pragma unroll
  for (int i = 0; i < 4; ++i) {
    int idx = t + (i << 8);
    int n = idx >> 4, k4 = (idx & 15) << 2;
    sx4 h, lo;
#pragma unroll
    for (int j = 0; j < 4; ++j) {
      float v = Tile[k4 + j][n];
      short hh = f2bf(v);
      h[j] = hh;
      lo[j] = f2bf(v - bf2f(hh));
    }
    *(sx4*)&Th[(size_t)(n0 + n) * K + k0 + k4] = h;
    *(sx4*)&Tl[(size_t)(n0 + n) * K + k0 + k4] = lo;
  }
}

// ---------- split-bf16 MFMA GEMM: C[M,N] = A[M,K] @ B[K,N] + bias ----------
// 64x64 tile, BK=32, 256 threads (4 waves, each 32x32 out).
// A: f32, split in-kernel. B: pre-split bf16 Bt[N][K]. 3 MFMAs per frag pair.
template<bool GATHER>
__global__ __launch_bounds__(256) void gemm_split_kernel(
    const float* __restrict__ A, const short* __restrict__ Bth,
    const short* __restrict__ Btl, const float* __restrict__ bias,
    float* __restrict__ C, int M, int N, int K)
{
  __shared__ short Ah[64][40], Al[64][40], Bh[64][40], Bl[64][40];
  const int t = threadIdx.x;
  const int bm = blockIdx.y << 6, bn = blockIdx.x << 6;
  const int ar = t >> 2, ak = (t & 3) << 3;   // A staging: row, k-offset (8 wide)
  const int bc = t >> 2, bk = (t & 3) << 3;   // B staging: col, k-offset

  int sp_base = 0;
  if (GATHER) {
    int gr = bm + ar;
    int b = gr >> 8, mm2 = gr & 255;
    int oh = mm2 >> 4, ow = mm2 & 15;
    sp_base = b * 4096 + oh * 256 + ow * 4;   // x spatial base (row-major HxW, *CC later)
  }
  const size_t brow = (size_t)(bn + bc) * K;

  float4 pa0, pa1; sx8 pbh, pbl;
  auto LOADG = [&](int k0) {
    int k = k0 + ak;
    const float* ap;
    if (GATHER) {
      int pos = k >> 8, ci = k & 255;
      ap = &A[(size_t)(sp_base + ((pos >> 2) << 6) + (pos & 3)) * 256 + ci];
    } else {
      ap = &A[(size_t)(bm + ar) * K + k];
    }
    pa0 = *(const float4*)ap;
    pa1 = *(const float4*)(ap + 4);
    pbh = *(const sx8*)&Bth[brow + k0 + bk];
    pbl = *(const sx8*)&Btl[brow + k0 + bk];
  };

  const int w = t >> 6, l = t & 63, g = l >> 4, c = l & 15;
  const int wr = w >> 1, wc = w & 1;
  const int ra0 = (wr << 5) + c, ra1 = ra0 + 16;
  const int cb0 = (wc << 5) + c, cb1 = cb0 + 16;
  const int g8 = g << 3;

  fx4 acc00 = {0.f,0.f,0.f,0.f}, acc01 = acc00, acc10 = acc00, acc11 = acc00;

  LOADG(0);
  for (int k0 = 0; k0 < K; k0 += 32) {
    // convert + stage
    sx4 AH0, AL0, AH1, AL1;
    AH0[0]=f2bf(pa0.x); AL0[0]=f2bf(pa0.x-bf2f(AH0[0]));
    AH0[1]=f2bf(pa0.y); AL0[1]=f2bf(pa0.y-bf2f(AH0[1]));
    AH0[2]=f2bf(pa0.z); AL0[2]=f2bf(pa0.z-bf2f(AH0[2]));
    AH0[3]=f2bf(pa0.w); AL0[3]=f2bf(pa0.w-bf2f(AH0[3]));
    AH1[0]=f2bf(pa1.x); AL1[0]=f2bf(pa1.x-bf2f(AH1[0]));
    AH1[1]=f2bf(pa1.y); AL1[1]=f2bf(pa1.y-bf2f(AH1[1]));
    AH1[2]=f2bf(pa1.z); AL1[2]=f2bf(pa1.z-bf2f(AH1[2]));
    AH1[3]=f2bf(pa1.w); AL1[3]=f2bf(pa1.w-bf2f(AH1[3]));
    *(sx4*)&Ah[ar][ak]     = AH0;  *(sx4*)&Ah[ar][ak + 4] = AH1;
    *(sx4*)&Al[ar][ak]     = AL0;  *(sx4*)&Al[ar][ak + 4] = AL1;
    *(sx8*)&Bh[bc][bk] = pbh;      *(sx8*)&Bl[bc][bk] = pbl;
    __syncthreads();
    if (k0 + 32 < K) LOADG(k0 + 32);   // prefetch next step under MFMA

    sx8 a0h = *(const sx8*)&Ah[ra0][g8];
    sx8 a0l = *(const sx8*)&Al[ra0][g8];
    sx8 a1h = *(const sx8*)&Ah[ra1][g8];
    sx8 a1l = *(const sx8*)&Al[ra1][g8];
    sx8 b0h = *(const sx8*)&Bh[cb0][g8];
    sx8 b0l = *(const sx8*)&Bl[cb0][g8];
    sx8 b1h = *(const sx8*)&Bh[cb1][g8];
    sx8 b1l = *(const sx8*)&Bl[cb1][g8];

    acc00 = __builtin_amdgcn_mfma_f32_16x16x32_bf16(a0h, b0h, acc00, 0, 0, 0);
    acc01 = __builtin_amdgcn_mfma_f32_16x16x32_bf16(a0h, b1h, acc01, 0, 0, 0);
    acc10 = __builtin_amdgcn_mfma_f32_16x16x32_bf16(a1h, b0h, acc10, 0, 0, 0);
    acc11 = __builtin_amdgcn_mfma_f32_16x16x32_bf16(a1h, b1h, acc11, 0, 0, 0);
    acc00 = __builtin_amdgcn_mfma_f32_16x16x32_bf16(a0l, b0h, acc00, 0, 0, 0);
    acc01 = __builtin_amdgcn_mfma_f32_16x16x32_bf16(a0l, b1h, acc01, 0, 0, 0);
    acc10 = __builtin_amdgcn_mfma_f32_16x16x32_bf16(a1l, b0h, acc10, 0, 0, 0);
    acc11 = __builtin_amdgcn_mfma_f32_16x16x32_bf16(a1l, b1h, acc11, 0, 0, 0);
    acc00 = __builtin_amdgcn_mfma_f32_16x16x32_bf16(a0h, b0l, acc00, 0, 0, 0);
    acc01 = __builtin_amdgcn_mfma_f32_16x16x32_bf16(a0h, b1l, acc01, 0, 0, 0);
    acc10 = __builtin_amdgcn_mfma_f32_16x16x32_bf16(a1h, b0l, acc10, 0, 0, 0);
    acc11 = __builtin_amdgcn_mfma_f32_16x16x32_bf16(a1h, b1l, acc11, 0, 0, 0);
    __syncthreads();
  }

  const int col0 = bn + (wc << 5);
  const float b0 = bias[col0 + c], b1 = bias[col0 + 16 + c];
  const int row0 = bm + (wr << 5) + (g << 2);
#pragma unroll
  for (int i = 0; i < 4; ++i) {
    C[(size_t)(row0 + i) * N + col0 + c]           = acc00[i] + b0;
    C[(size_t)(row0 + i) * N + col0 + 16 + c]      = acc01[i] + b1;
    C[(size_t)(row0 + 16 + i) * N + col0 + c]      = acc10[i] + b0;
    C[(size_t)(row0 + 16 + i) * N + col0 + 16 + c] = acc11[i] + b1;
  }
}

// ---------------- LayerNorm over last dim (C=256), one block per row ----------------
__global__ __launch_bounds__(256) void ln_kernel(
    float* __restrict__ xs, const float* __restrict__ g, const float* __restrict__ bta)
{
  const int row = blockIdx.x, t = threadIdx.x;
  float v = xs[(size_t)row * CC + t];
  float s = v, s2 = v * v;
#pragma unroll
  for (int off = 32; off; off >>= 1) {
    s  += __shfl_xor(s,  off, 64);
    s2 += __shfl_xor(s2, off, 64);
  }
  __shared__ float red[8];
  const int w = t >> 6, lane = t & 63;
  if (lane == 0) { red[w] = s; red[4 + w] = s2; }
  __syncthreads();
  float ts  = red[0] + red[1] + red[2] + red[3];
  float ts2 = red[4] + red[5] + red[6] + red[7];
  float mu  = ts * (1.0f / 256.0f);
  float var = ts2 * (1.0f / 256.0f) - mu * mu;
  float o = (v - mu) * rsqrtf(var + 1e-6f) * g[t] + bta[t];
  xs[(size_t)row * CC + t] = o;
}

// ---------------- MFMA attention: 32 q-rows / block, one (b,h), 4 waves ----------------
__global__ __launch_bounds__(256) void attn_mfma_kernel(
    float* __restrict__ q, const float* __restrict__ kv)
{
  __shared__ short Ks[256*36];
  __shared__ short Vt[32*264];
  __shared__ short Ps[32*264];
  __shared__ float redm[4][16];
  __shared__ float reds[4][16];

  const int tid = threadIdx.x;
  const int bid = blockIdx.x;
  const int nt = bid & 127, h = (bid >> 7) & 7, b = bid >> 10;
  const int n0 = nt << 5;
  const size_t kvbase = (size_t)(b * MM) * (2*CC) + h * HD;

  {
    const int d0 = (tid & 7) << 2;
    const int mb = tid >> 3;
#pragma unroll
    for (int it = 0; it < 8; ++it) {
      int m = mb + (it << 5);
      float4 kf = *(const float4*)&kv[kvbase + (size_t)m*(2*CC) + d0];
      sx4 kk = { f2bf(kf.x), f2bf(kf.y), f2bf(kf.z), f2bf(kf.w) };
      *(sx4*)&Ks[m*36 + d0] = kk;
      float4 vf = *(const float4*)&kv[kvbase + (size_t)m*(2*CC) + CC + d0];
      Vt[(d0+0)*264 + m] = f2bf(vf.x);
      Vt[(d0+1)*264 + m] = f2bf(vf.y);
      Vt[(d0+2)*264 + m] = f2bf(vf.z);
      Vt[(d0+3)*264 + m] = f2bf(vf.w);
    }
  }

  const int w  = tid >> 6, l = tid & 63;
  const int g  = l >> 4,  c = l & 15;
  const int rg = w >> 1,  ch = w & 1;

  sx8 aq;
  {
    const float* qp = q + ((size_t)(b*NN + n0 + rg*16 + c))*CC + h*HD + (g<<3);
    float4 qa = *(const float4*)qp;
    float4 qb = *(const float4*)(qp + 4);
    aq[0]=f2bf(qa.x*SCALE_); aq[1]=f2bf(qa.y*SCALE_); aq[2]=f2bf(qa.z*SCALE_); aq[3]=f2bf(qa.w*SCALE_);
    aq[4]=f2bf(qb.x*SCALE_); aq[5]=f2bf(qb.y*SCALE_); aq[6]=f2bf(qb.z*SCALE_); aq[7]=f2bf(qb.w*SCALE_);
  }
  __syncthreads();

  fx4 acc[8];
#pragma unroll
  for (int j = 0; j < 8; ++j) {
    int tt  = (ch << 3) + j;
    int row = tt*16 + c;
    sx4 b0 = *(const sx4*)&Ks[row*36 + (g<<3)];
    sx4 b1 = *(const sx4*)&Ks[row*36 + (g<<3) + 4];
    sx8 bk = { b0[0],b0[1],b0[2],b0[3], b1[0],b1[1],b1[2],b1[3] };
    fx4 z = {0.f,0.f,0.f,0.f};
    acc[j] = __builtin_amdgcn_mfma_f32_16x16x32_bf16(aq, bk, z, 0, 0, 0);
  }

  float mx[4], sm[4];
#pragma unroll
  for (int i = 0; i < 4; ++i) {
    float m0 = acc[0][i];
#pragma unroll
    for (int j = 1; j < 8; ++j) m0 = fmaxf(m0, acc[j][i]);
    m0 = fmaxf(m0, __shfl_xor(m0, 1, 64));
    m0 = fmaxf(m0, __shfl_xor(m0, 2, 64));
    m0 = fmaxf(m0, __shfl_xor(m0, 4, 64));
    m0 = fmaxf(m0, __shfl_xor(m0, 8, 64));
    mx[i] = m0;
  }
  if (c == 0) {
#pragma unroll
    for (int i = 0; i < 4; ++i) redm[w][(g<<2)+i] = mx[i];
  }
  __syncthreads();

#pragma unroll
  for (int i = 0; i < 4; ++i) {
    float M  = fmaxf(mx[i], redm[w^1][(g<<2)+i]);
    float s0 = 0.f;
#pragma unroll
    for (int j = 0; j < 8; ++j) { float p = __expf(acc[j][i] - M); acc[j][i] = p; s0 += p; }
    s0 += __shfl_xor(s0, 1, 64);
    s0 += __shfl_xor(s0, 2, 64);
    s0 += __shfl_xor(s0, 4, 64);
    s0 += __shfl_xor(s0, 8, 64);
    sm[i] = s0;
  }
  if (c == 0) {
#pragma unroll
    for (int i = 0; i < 4; ++i) reds[w][(g<<2)+i] = sm[i];
  }
#pragma unroll
  for (int j = 0; j < 8; ++j) {
#pragma unroll
    for (int i = 0; i < 4; ++i)
      Ps[(rg*16 + (g<<2)+i)*264 + (ch<<7) + j*16 + c] = f2bf(acc[j][i]);
  }
  __syncthreads();

  fx4 o = {0.f,0.f,0.f,0.f};
#pragma unroll
  for (int s = 0; s < 8; ++s) {
    sx8 ap = *(const sx8*)&Ps[(rg*16 + c)*264 + (s<<5) + (g<<3)];
    sx8 bv = *(const sx8*)&Vt[(ch*16 + c)*264 + (s<<5) + (g<<3)];
    o = __builtin_amdgcn_mfma_f32_16x16x32_bf16(ap, bv, o, 0, 0, 0);
  }
#pragma unroll
  for (int i = 0; i < 4; ++i) {
    float tot = reds[w][(g<<2)+i] + reds[w^1][(g<<2)+i];
    float ov  = o[i] / tot;
    q[((size_t)(b*NN + n0 + rg*16 + (g<<2)+i))*CC + h*HD + ch*16 + c] = ov;
  }
}

extern "C" void kernel_launch(void* const* d_in, const int* in_sizes, int n_in,
                              void* d_out, int out_size, void* d_ws, size_t ws_size,
                              hipStream_t stream) {
  const float* x      = (const float*)d_in[0];
  const float* q_w    = (const float*)d_in[1];
  const float* q_b    = (const float*)d_in[2];
  const float* kv_w   = (const float*)d_in[3];
  const float* kv_b   = (const float*)d_in[4];
  const float* sr_w   = (const float*)d_in[5];
  const float* sr_b   = (const float*)d_in[6];
  const float* norm_g = (const float*)d_in[7];
  const float* norm_b = (const float*)d_in[8];
  const float* proj_w = (const float*)d_in[9];
  const float* proj_b = (const float*)d_in[10];
  float* out = (float*)d_out;

  float* qbuf  = (float*)d_ws;                    // B*N*C  fp32
  float* xsbuf = qbuf + (size_t)B_ * NN * CC;     // B*M*C
  float* kvbuf = xsbuf + (size_t)B_ * MM * CC;    // B*M*2C
  short* qwt_h  = (short*)(kvbuf + (size_t)B_ * MM * 2 * CC);
  short* qwt_l  = qwt_h + 65536;
  short* kvwt_h = qwt_l + 65536;
  short* kvwt_l = kvwt_h + 131072;
  short* pwt_h  = kvwt_l + 131072;
  short* pwt_l  = pwt_h + 65536;
  short* swt_h  = pwt_l + 65536;
  short* swt_l  = swt_h + 1048576;

  dim3 blk(256);

  // pre-split weights (transposed to [N][K] bf16 hi/lo)
  wsplit_kernel<<<dim3(CC/64, CC/64), blk, 0, stream>>>(q_w, qwt_h, qwt_l, CC, CC);
  wsplit_kernel<<<dim3(2*CC/64, CC/64), blk, 0, stream>>>(kv_w, kvwt_h, kvwt_l, CC, 2*CC);
  wsplit_kernel<<<dim3(CC/64, CC/64), blk, 0, stream>>>(proj_w, pwt_h, pwt_l, CC, CC);
  wsplit_kernel<<<dim3(CC/64, 4096/64), blk, 0, stream>>>(sr_w, swt_h, swt_l, 4096, CC);

  // 1) q = x @ q_w + q_b
  gemm_split_kernel<false><<<dim3(CC/64, (B_*NN)/64), blk, 0, stream>>>(
      x, qwt_h, qwt_l, q_b, qbuf, B_*NN, CC, CC);

  // 2) xs = stride-4 conv (gathered GEMM, K=4096)
  gemm_split_kernel<true><<<dim3(CC/64, (B_*MM)/64), blk, 0, stream>>>(
      x, swt_h, swt_l, sr_b, xsbuf, B_*MM, CC, 4096);

  // 3) LayerNorm
  ln_kernel<<<B_ * MM, blk, 0, stream>>>(xsbuf, norm_g, norm_b);

  // 4) kv = xs @ kv_w + kv_b
  gemm_split_kernel<false><<<dim3((2*CC)/64, (B_*MM)/64), blk, 0, stream>>>(
      xsbuf, kvwt_h, kvwt_l, kv_b, kvbuf, B_*MM, 2*CC, CC);

  // 5) attention in place over qbuf
  attn_mfma_kernel<<<B_ * NH * (NN / 32), blk, 0, stream>>>(qbuf, kvbuf);

  // 6) out = attn_out @ proj_w + proj_b
  gemm_split_kernel<false><<<dim3(CC/64, (B_*NN)/64), blk, 0, stream>>>(
      qbuf, pwt_h, pwt_l, proj_b, out, B_*NN, CC, CC);
}

// Round 6
// 300.916 us; speedup vs baseline: 3.6016x; 1.1826x over previous
//
#include <hip/hip_runtime.h>
#include <math.h>

#define B_   16
#define CC   256
#define NN   4096   // 64*64
#define MM   256    // 16*16
#define NH   8
#define HD   32
// scale * log2(e): softmax done in base-2
#define QSCALE (0.17677669529663687f * 1.4426950408889634f)

typedef float fx4 __attribute__((ext_vector_type(4)));
typedef short sx4 __attribute__((ext_vector_type(4)));
typedef short sx8 __attribute__((ext_vector_type(8)));

__device__ inline short f2bf(float f) {
  unsigned u = __builtin_bit_cast(unsigned, f);
  u += 0x7FFFu + ((u >> 16) & 1u);   // RNE
  return (short)(u >> 16);
}
__device__ inline float bf2f(short s) {
  unsigned u = ((unsigned)(unsigned short)s) << 16;
  return __builtin_bit_cast(float, u);
}
__device__ inline float fexp2(float x) {
#if __has_builtin(__builtin_amdgcn_exp2f)
  return __builtin_amdgcn_exp2f(x);
#else
  return exp2f(x);
#endif
}
__device__ inline float frcp(float x) {
#if __has_builtin(__builtin_amdgcn_rcpf)
  return __builtin_amdgcn_rcpf(x);
#else
  return 1.0f / x;
#endif
}

// ---------- weight transpose + bf16 split: W[K][N] f32 -> Th/Tl[N][K] bf16 ----------
__global__ __launch_bounds__(256) void wsplit_kernel(
    const float* __restrict__ W, short* __restrict__ Th, short* __restrict__ Tl,
    int K, int N)
{
  __shared__ float Tile[64][65];
  const int t = threadIdx.x;
  const int k0 = blockIdx.y << 6, n0 = blockIdx.x << 6;
#pragma unroll
  for (int i = 0; i < 4; ++i) {
    int idx = t + (i << 8);
    int k = idx >> 4, n4 = (idx & 15) << 2;
    float4 v = *(const float4*)&W[(size_t)(k0 + k) * N + n0 + n4];
    Tile[k][n4 + 0] = v.x; Tile[k][n4 + 1] = v.y;
    Tile[k][n4 + 2] = v.z; Tile[k][n4 + 3] = v.w;
  }
  __syncthreads();
#pragma unroll
  for (int i = 0; i < 4; ++i) {
    int idx = t + (i << 8);
    int n = idx >> 4, k4 = (idx & 15) << 2;
    sx4 h, lo;
#pragma unroll
    for (int j = 0; j < 4; ++j) {
      float v = Tile[k4 + j][n];
      short hh = f2bf(v);
      h[j] = hh;
      lo[j] = f2bf(v - bf2f(hh));
    }
    *(sx4*)&Th[(size_t)(n0 + n) * K + k0 + k4] = h;
    *(sx4*)&Tl[(size_t)(n0 + n) * K + k0 + k4] = lo;
  }
}

// ---------- split-bf16 MFMA GEMM: C[M,N] = A[M,K] @ B[K,N] + bias ----------
// EPI 0: f32 C row-major.  EPI 2: kv mode -> bf16 K/V buffers [b*8+h][m][32].
template<bool GATHER, int EPI>
__global__ __launch_bounds__(256) void gemm_split_kernel(
    const float* __restrict__ A, const short* __restrict__ Bth,
    const short* __restrict__ Btl, const float* __restrict__ bias,
    float* __restrict__ C, short* __restrict__ kout, short* __restrict__ vout,
    int M, int N, int K)
{
  __shared__ short Ah[64][40], Al[64][40], Bh[64][40], Bl[64][40];
  const int t = threadIdx.x;
  const int bm = blockIdx.y << 6, bn = blockIdx.x << 6;
  const int ar = t >> 2, ak = (t & 3) << 3;
  const int bc = t >> 2, bk = (t & 3) << 3;

  int sp_base = 0;
  if (GATHER) {
    int gr = bm + ar;
    int b = gr >> 8, mm2 = gr & 255;
    int oh = mm2 >> 4, ow = mm2 & 15;
    sp_base = b * 4096 + oh * 256 + ow * 4;
  }
  const size_t brow = (size_t)(bn + bc) * K;

  float4 pa0, pa1; sx8 pbh, pbl;
  auto LOADG = [&](int k0) {
    int k = k0 + ak;
    const float* ap;
    if (GATHER) {
      int pos = k >> 8, ci = k & 255;
      ap = &A[(size_t)(sp_base + ((pos >> 2) << 6) + (pos & 3)) * 256 + ci];
    } else {
      ap = &A[(size_t)(bm + ar) * K + k];
    }
    pa0 = *(const float4*)ap;
    pa1 = *(const float4*)(ap + 4);
    pbh = *(const sx8*)&Bth[brow + k0 + bk];
    pbl = *(const sx8*)&Btl[brow + k0 + bk];
  };

  const int w = t >> 6, l = t & 63, g = l >> 4, c = l & 15;
  const int wr = w >> 1, wc = w & 1;
  const int ra0 = (wr << 5) + c, ra1 = ra0 + 16;
  const int cb0 = (wc << 5) + c, cb1 = cb0 + 16;
  const int g8 = g << 3;

  fx4 acc00 = {0.f,0.f,0.f,0.f}, acc01 = acc00, acc10 = acc00, acc11 = acc00;

  LOADG(0);
  for (int k0 = 0; k0 < K; k0 += 32) {
    sx4 AH0, AL0, AH1, AL1;
    AH0[0]=f2bf(pa0.x); AL0[0]=f2bf(pa0.x-bf2f(AH0[0]));
    AH0[1]=f2bf(pa0.y); AL0[1]=f2bf(pa0.y-bf2f(AH0[1]));
    AH0[2]=f2bf(pa0.z); AL0[2]=f2bf(pa0.z-bf2f(AH0[2]));
    AH0[3]=f2bf(pa0.w); AL0[3]=f2bf(pa0.w-bf2f(AH0[3]));
    AH1[0]=f2bf(pa1.x); AL1[0]=f2bf(pa1.x-bf2f(AH1[0]));
    AH1[1]=f2bf(pa1.y); AL1[1]=f2bf(pa1.y-bf2f(AH1[1]));
    AH1[2]=f2bf(pa1.z); AL1[2]=f2bf(pa1.z-bf2f(AH1[2]));
    AH1[3]=f2bf(pa1.w); AL1[3]=f2bf(pa1.w-bf2f(AH1[3]));
    *(sx4*)&Ah[ar][ak]     = AH0;  *(sx4*)&Ah[ar][ak + 4] = AH1;
    *(sx4*)&Al[ar][ak]     = AL0;  *(sx4*)&Al[ar][ak + 4] = AL1;
    *(sx8*)&Bh[bc][bk] = pbh;      *(sx8*)&Bl[bc][bk] = pbl;
    __syncthreads();
    if (k0 + 32 < K) LOADG(k0 + 32);

    sx8 a0h = *(const sx8*)&Ah[ra0][g8];
    sx8 a0l = *(const sx8*)&Al[ra0][g8];
    sx8 a1h = *(const sx8*)&Ah[ra1][g8];
    sx8 a1l = *(const sx8*)&Al[ra1][g8];
    sx8 b0h = *(const sx8*)&Bh[cb0][g8];
    sx8 b0l = *(const sx8*)&Bl[cb0][g8];
    sx8 b1h = *(const sx8*)&Bh[cb1][g8];
    sx8 b1l = *(const sx8*)&Bl[cb1][g8];

    acc00 = __builtin_amdgcn_mfma_f32_16x16x32_bf16(a0h, b0h, acc00, 0, 0, 0);
    acc01 = __builtin_amdgcn_mfma_f32_16x16x32_bf16(a0h, b1h, acc01, 0, 0, 0);
    acc10 = __builtin_amdgcn_mfma_f32_16x16x32_bf16(a1h, b0h, acc10, 0, 0, 0);
    acc11 = __builtin_amdgcn_mfma_f32_16x16x32_bf16(a1h, b1h, acc11, 0, 0, 0);
    acc00 = __builtin_amdgcn_mfma_f32_16x16x32_bf16(a0l, b0h, acc00, 0, 0, 0);
    acc01 = __builtin_amdgcn_mfma_f32_16x16x32_bf16(a0l, b1h, acc01, 0, 0, 0);
    acc10 = __builtin_amdgcn_mfma_f32_16x16x32_bf16(a1l, b0h, acc10, 0, 0, 0);
    acc11 = __builtin_amdgcn_mfma_f32_16x16x32_bf16(a1l, b1h, acc11, 0, 0, 0);
    acc00 = __builtin_amdgcn_mfma_f32_16x16x32_bf16(a0h, b0l, acc00, 0, 0, 0);
    acc01 = __builtin_amdgcn_mfma_f32_16x16x32_bf16(a0h, b1l, acc01, 0, 0, 0);
    acc10 = __builtin_amdgcn_mfma_f32_16x16x32_bf16(a1h, b0l, acc10, 0, 0, 0);
    acc11 = __builtin_amdgcn_mfma_f32_16x16x32_bf16(a1h, b1l, acc11, 0, 0, 0);
    __syncthreads();
  }

  const int col0 = bn + (wc << 5);
  const float b0 = bias[col0 + c], b1 = bias[col0 + 16 + c];
  const int row0 = bm + (wr << 5) + (g << 2);
  if constexpr (EPI == 0) {
#pragma unroll
    for (int i = 0; i < 4; ++i) {
      C[(size_t)(row0 + i) * N + col0 + c]           = acc00[i] + b0;
      C[(size_t)(row0 + i) * N + col0 + 16 + c]      = acc01[i] + b1;
      C[(size_t)(row0 + 16 + i) * N + col0 + c]      = acc10[i] + b0;
      C[(size_t)(row0 + 16 + i) * N + col0 + 16 + c] = acc11[i] + b1;
    }
  } else {
    // kv mode: n<256 -> K head (h=n>>5,d=n&31); n>=256 -> V. [b*8+h][m][32] bf16.
    auto emit = [&](int row, int n, float v) {
      int b = row >> 8, m = row & 255;
      short* dst = (n < 256) ? kout : vout;
      int nn = n & 255;
      int h = nn >> 5, d = nn & 31;
      dst[(size_t)(((b << 3) + h) * 256 + m) * 32 + d] = f2bf(v);
    };
#pragma unroll
    for (int i = 0; i < 4; ++i) {
      emit(row0 + i,      col0 + c,      acc00[i] + b0);
      emit(row0 + i,      col0 + 16 + c, acc01[i] + b1);
      emit(row0 + 16 + i, col0 + c,      acc10[i] + b0);
      emit(row0 + 16 + i, col0 + 16 + c, acc11[i] + b1);
    }
  }
}

// ---------------- LayerNorm over last dim (C=256), one block per row ----------------
__global__ __launch_bounds__(256) void ln_kernel(
    float* __restrict__ xs, const float* __restrict__ g, const float* __restrict__ bta)
{
  const int row = blockIdx.x, t = threadIdx.x;
  float v = xs[(size_t)row * CC + t];
  float s = v, s2 = v * v;
#pragma unroll
  for (int off = 32; off; off >>= 1) {
    s  += __shfl_xor(s,  off, 64);
    s2 += __shfl_xor(s2, off, 64);
  }
  __shared__ float red[8];
  const int w = t >> 6, lane = t & 63;
  if (lane == 0) { red[w] = s; red[4 + w] = s2; }
  __syncthreads();
  float ts  = red[0] + red[1] + red[2] + red[3];
  float ts2 = red[4] + red[5] + red[6] + red[7];
  float mu  = ts * (1.0f / 256.0f);
  float var = ts2 * (1.0f / 256.0f) - mu * mu;
  float o = (v - mu) * rsqrtf(var + 1e-6f) * g[t] + bta[t];
  xs[(size_t)row * CC + t] = o;
}

// ---------------- MFMA attention v2: 64 q-rows / block, 4 independent waves ----------------
// K from global (bf16, L1/L2-resident); V transposed into LDS; P in LDS per wave.
// Softmax in log2 space, fully in-register per wave. One barrier total.
__global__ __launch_bounds__(256, 3) void attn_mfma2_kernel(
    float* __restrict__ q, const short* __restrict__ kbf, const short* __restrict__ vbf)
{
  __shared__ short Vt[32 * 264];       // V^T [d][m], stride 264
  __shared__ short Ps[4 * 16 * 264];   // per-wave P [16][264]

  const int tid = threadIdx.x;
  const int bid = blockIdx.x;
  const int nt = bid & 63, h = (bid >> 6) & 7, b = bid >> 9;
  const int n0 = nt << 6;
  const int bh = (b << 3) + h;
  const short* kb = kbf + (size_t)bh * 256 * 32;
  const short* vb = vbf + (size_t)bh * 256 * 32;

  // ---- stage V^T: thread owns m=tid, reads v[m][0..31], scatters to Vt[d][m] ----
  {
    sx8 v0 = *(const sx8*)&vb[tid * 32 + 0];
    sx8 v1 = *(const sx8*)&vb[tid * 32 + 8];
    sx8 v2 = *(const sx8*)&vb[tid * 32 + 16];
    sx8 v3 = *(const sx8*)&vb[tid * 32 + 24];
#pragma unroll
    for (int e = 0; e < 8; ++e) {
      Vt[(e)      * 264 + tid] = v0[e];
      Vt[(8 + e)  * 264 + tid] = v1[e];
      Vt[(16 + e) * 264 + tid] = v2[e];
      Vt[(24 + e) * 264 + tid] = v3[e];
    }
  }

  const int w = tid >> 6, l = tid & 63;
  const int g = l >> 4, c = l & 15;

  // ---- Q A-fragment from global f32 (row c of wave tile), scale*log2e folded ----
  sx8 aq;
  {
    const float* qp = q + ((size_t)(b * NN + n0 + w * 16 + c)) * CC + h * HD + (g << 3);
    float4 qa = *(const float4*)qp;
    float4 qb = *(const float4*)(qp + 4);
    aq[0]=f2bf(qa.x*QSCALE); aq[1]=f2bf(qa.y*QSCALE); aq[2]=f2bf(qa.z*QSCALE); aq[3]=f2bf(qa.w*QSCALE);
    aq[4]=f2bf(qb.x*QSCALE); aq[5]=f2bf(qb.y*QSCALE); aq[6]=f2bf(qb.z*QSCALE); aq[7]=f2bf(qb.w*QSCALE);
  }

  // ---- S = Q K^T : 16 tiles, B-frags straight from global (1KB dense per load) ----
  fx4 acc[16];
#pragma unroll
  for (int j = 0; j < 16; ++j) {
    sx8 bk = *(const sx8*)&kb[(j * 16 + c) * 32 + (g << 3)];
    fx4 z = {0.f, 0.f, 0.f, 0.f};
    acc[j] = __builtin_amdgcn_mfma_f32_16x16x32_bf16(aq, bk, z, 0, 0, 0);
  }

  // ---- in-register softmax over full row (lane holds rows 4g+i, cols 16j+c) ----
  float mx[4], sm[4];
#pragma unroll
  for (int i = 0; i < 4; ++i) {
    float m0 = acc[0][i];
#pragma unroll
    for (int j = 1; j < 16; ++j) m0 = fmaxf(m0, acc[j][i]);
    m0 = fmaxf(m0, __shfl_xor(m0, 1, 64));
    m0 = fmaxf(m0, __shfl_xor(m0, 2, 64));
    m0 = fmaxf(m0, __shfl_xor(m0, 4, 64));
    m0 = fmaxf(m0, __shfl_xor(m0, 8, 64));
    mx[i] = m0;
  }
#pragma unroll
  for (int i = 0; i < 4; ++i) {
    float s0 = 0.f;
#pragma unroll
    for (int j = 0; j < 16; ++j) {
      float p = fexp2(acc[j][i] - mx[i]);
      acc[j][i] = p; s0 += p;
    }
    s0 += __shfl_xor(s0, 1, 64);
    s0 += __shfl_xor(s0, 2, 64);
    s0 += __shfl_xor(s0, 4, 64);
    s0 += __shfl_xor(s0, 8, 64);
    sm[i] = s0;
  }

  // ---- P (unnormalized, bf16) -> LDS, own wave region only ----
  const int pbase = (w << 4) * 264;
#pragma unroll
  for (int j = 0; j < 16; ++j) {
#pragma unroll
    for (int i = 0; i < 4; ++i)
      Ps[pbase + ((g << 2) + i) * 264 + (j << 4) + c] = f2bf(acc[j][i]);
  }

  __syncthreads();   // covers Vt staging + P visibility

  // ---- O = P V : 8 k-steps, two 16-col d-tiles ----
  fx4 o0 = {0.f,0.f,0.f,0.f}, o1 = {0.f,0.f,0.f,0.f};
#pragma unroll
  for (int s = 0; s < 8; ++s) {
    sx8 ap  = *(const sx8*)&Ps[pbase + c * 264 + (s << 5) + (g << 3)];
    sx8 bv0 = *(const sx8*)&Vt[(c)      * 264 + (s << 5) + (g << 3)];
    sx8 bv1 = *(const sx8*)&Vt[(16 + c) * 264 + (s << 5) + (g << 3)];
    o0 = __builtin_amdgcn_mfma_f32_16x16x32_bf16(ap, bv0, o0, 0, 0, 0);
    o1 = __builtin_amdgcn_mfma_f32_16x16x32_bf16(ap, bv1, o1, 0, 0, 0);
  }

  // ---- normalize + write O in place over q ----
#pragma unroll
  for (int i = 0; i < 4; ++i) {
    float inv = frcp(sm[i]);
    size_t row = (size_t)(b * NN + n0 + w * 16 + (g << 2) + i) * CC + h * HD;
    q[row + c]      = o0[i] * inv;
    q[row + 16 + c] = o1[i] * inv;
  }
}

extern "C" void kernel_launch(void* const* d_in, const int* in_sizes, int n_in,
                              void* d_out, int out_size, void* d_ws, size_t ws_size,
                              hipStream_t stream) {
  const float* x      = (const float*)d_in[0];
  const float* q_w    = (const float*)d_in[1];
  const float* q_b    = (const float*)d_in[2];
  const float* kv_w   = (const float*)d_in[3];
  const float* kv_b   = (const float*)d_in[4];
  const float* sr_w   = (const float*)d_in[5];
  const float* sr_b   = (const float*)d_in[6];
  const float* norm_g = (const float*)d_in[7];
  const float* norm_b = (const float*)d_in[8];
  const float* proj_w = (const float*)d_in[9];
  const float* proj_b = (const float*)d_in[10];
  float* out = (float*)d_out;

  float* qbuf  = (float*)d_ws;                       // B*N*C f32 (Q then O in-place)
  float* xsbuf = qbuf + (size_t)B_ * NN * CC;        // B*M*C f32
  short* kbf   = (short*)(xsbuf + (size_t)B_ * MM * CC);  // [128][256][32] bf16
  short* vbf   = kbf + (size_t)128 * 256 * 32;
  short* qwt_h  = vbf + (size_t)128 * 256 * 32;
  short* qwt_l  = qwt_h + 65536;
  short* kvwt_h = qwt_l + 65536;
  short* kvwt_l = kvwt_h + 131072;
  short* pwt_h  = kvwt_l + 131072;
  short* pwt_l  = pwt_h + 65536;
  short* swt_h  = pwt_l + 65536;
  short* swt_l  = swt_h + 1048576;

  dim3 blk(256);

  wsplit_kernel<<<dim3(CC/64, CC/64), blk, 0, stream>>>(q_w, qwt_h, qwt_l, CC, CC);
  wsplit_kernel<<<dim3(2*CC/64, CC/64), blk, 0, stream>>>(kv_w, kvwt_h, kvwt_l, CC, 2*CC);
  wsplit_kernel<<<dim3(CC/64, CC/64), blk, 0, stream>>>(proj_w, pwt_h, pwt_l, CC, CC);
  wsplit_kernel<<<dim3(CC/64, 4096/64), blk, 0, stream>>>(sr_w, swt_h, swt_l, 4096, CC);

  // 1) q = x @ q_w + q_b  (f32 out)
  gemm_split_kernel<false,0><<<dim3(CC/64, (B_*NN)/64), blk, 0, stream>>>(
      x, qwt_h, qwt_l, q_b, qbuf, nullptr, nullptr, B_*NN, CC, CC);

  // 2) xs = stride-4 conv (gathered GEMM, K=4096)
  gemm_split_kernel<true,0><<<dim3(CC/64, (B_*MM)/64), blk, 0, stream>>>(
      x, swt_h, swt_l, sr_b, xsbuf, nullptr, nullptr, B_*MM, CC, 4096);

  // 3) LayerNorm
  ln_kernel<<<B_ * MM, blk, 0, stream>>>(xsbuf, norm_g, norm_b);

  // 4) kv = xs @ kv_w + kv_b  -> bf16 K[bh][m][32], V[bh][m][32]
  gemm_split_kernel<false,2><<<dim3((2*CC)/64, (B_*MM)/64), blk, 0, stream>>>(
      xsbuf, kvwt_h, kvwt_l, kv_b, nullptr, kbf, vbf, B_*MM, 2*CC, CC);

  // 5) attention in place over qbuf (8192 blocks, 64 rows each)
  attn_mfma2_kernel<<<B_ * NH * (NN / 64), blk, 0, stream>>>(qbuf, kbf, vbf);

  // 6) out = attn_out @ proj_w + proj_b
  gemm_split_kernel<false,0><<<dim3(CC/64, (B_*NN)/64), blk, 0, stream>>>(
      qbuf, pwt_h, pwt_l, proj_b, out, nullptr, nullptr, B_*NN, CC, CC);
}

// Round 7
// 237.443 us; speedup vs baseline: 4.5644x; 1.2673x over previous
//
#include <hip/hip_runtime.h>
#include <math.h>

#define B_   16
#define CC   256
#define NN   4096   // 64*64
#define MM   256    // 16*16
#define NH   8
#define HD   32
// scale * log2(e): softmax done in base-2
#define QSCALE (0.17677669529663687f * 1.4426950408889634f)

typedef float fx4 __attribute__((ext_vector_type(4)));
typedef short sx4 __attribute__((ext_vector_type(4)));
typedef short sx8 __attribute__((ext_vector_type(8)));

__device__ inline short f2bf(float f) {
  unsigned u = __builtin_bit_cast(unsigned, f);
  u += 0x7FFFu + ((u >> 16) & 1u);   // RNE
  return (short)(u >> 16);
}
__device__ inline float bf2f(short s) {
  unsigned u = ((unsigned)(unsigned short)s) << 16;
  return __builtin_bit_cast(float, u);
}
__device__ inline float fexp2(float x) {
#if __has_builtin(__builtin_amdgcn_exp2f)
  return __builtin_amdgcn_exp2f(x);
#else
  return exp2f(x);
#endif
}
__device__ inline float frcp(float x) {
#if __has_builtin(__builtin_amdgcn_rcpf)
  return __builtin_amdgcn_rcpf(x);
#else
  return 1.0f / x;
#endif
}

// ---------- weight transpose + bf16 split: W[K][N] f32 -> Th/Tl[N][K] bf16 ----------
__global__ __launch_bounds__(256) void wsplit_kernel(
    const float* __restrict__ W, short* __restrict__ Th, short* __restrict__ Tl,
    int K, int N)
{
  __shared__ float Tile[64][65];
  const int t = threadIdx.x;
  const int k0 = blockIdx.y << 6, n0 = blockIdx.x << 6;
#pragma unroll
  for (int i = 0; i < 4; ++i) {
    int idx = t + (i << 8);
    int k = idx >> 4, n4 = (idx & 15) << 2;
    float4 v = *(const float4*)&W[(size_t)(k0 + k) * N + n0 + n4];
    Tile[k][n4 + 0] = v.x; Tile[k][n4 + 1] = v.y;
    Tile[k][n4 + 2] = v.z; Tile[k][n4 + 3] = v.w;
  }
  __syncthreads();
#pragma unroll
  for (int i = 0; i < 4; ++i) {
    int idx = t + (i << 8);
    int n = idx >> 4, k4 = (idx & 15) << 2;
    sx4 h, lo;
#pragma unroll
    for (int j = 0; j < 4; ++j) {
      float v = Tile[k4 + j][n];
      short hh = f2bf(v);
      h[j] = hh;
      lo[j] = f2bf(v - bf2f(hh));
    }
    *(sx4*)&Th[(size_t)(n0 + n) * K + k0 + k4] = h;
    *(sx4*)&Tl[(size_t)(n0 + n) * K + k0 + k4] = lo;
  }
}

// ---------- split-bf16 MFMA GEMM: C[M,N] = A[M,K] @ B[K,N] + bias ----------
// AMODE: 0 = A f32 row-major; 1 = A f32 conv-gather; 2 = A pre-split bf16 head-major
//        ([b*8+h][n][32], logical row=b*4096+n, col=h*32+d).
// EPI:   0 = f32 C + bias; 1 = f32 K-split partial (no bias, z-offset);
//        2 = kv -> bf16 K/V [b*8+h][m][32]; 3 = q -> bf16 prescaled [b*8+h][n][32].
template<int AMODE, int EPI>
__global__ __launch_bounds__(256) void gemm_split_kernel(
    const void* __restrict__ Av, const short* __restrict__ Alo,
    const short* __restrict__ Bth, const short* __restrict__ Btl,
    const float* __restrict__ bias,
    float* __restrict__ C, short* __restrict__ kout, short* __restrict__ vout,
    int M, int N, int K)
{
  __shared__ short Ah[64][40], Al[64][40], Bh[64][40], Bl[64][40];
  const int t = threadIdx.x;
  const int bm = blockIdx.y << 6, bn = blockIdx.x << 6;
  const int ar = t >> 2, ak = (t & 3) << 3;
  const int bc = t >> 2, bk = (t & 3) << 3;
  const float* Af  = (const float*)Av;
  const short* Ahg = (const short*)Av;

  int sp_base = 0;
  if (AMODE == 1) {
    int gr = bm + ar;
    int b = gr >> 8, mm2 = gr & 255;
    int oh = mm2 >> 4, ow = mm2 & 15;
    sp_base = b * 4096 + oh * 256 + ow * 4;
  }
  const size_t brow = (size_t)(bn + bc) * K;

  const int KS = K / gridDim.z;
  const int kbeg = blockIdx.z * KS, kend = kbeg + KS;

  float4 pa0, pa1; sx8 pah, pal, pbh, pbl;
  auto LOADG = [&](int k0) {
    int k = k0 + ak;
    if constexpr (AMODE == 2) {
      int row = bm + ar;
      int b = row >> 12, n = row & 4095;
      size_t idx = ((size_t)b << 20) + ((size_t)(k >> 5) << 17) + ((size_t)n << 5) + (k & 31);
      pah = *(const sx8*)&Ahg[idx];
      pal = *(const sx8*)&Alo[idx];
    } else {
      const float* ap;
      if constexpr (AMODE == 1) {
        int pos = k >> 8, ci = k & 255;
        ap = &Af[(size_t)(sp_base + ((pos >> 2) << 6) + (pos & 3)) * 256 + ci];
      } else {
        ap = &Af[(size_t)(bm + ar) * K + k];
      }
      pa0 = *(const float4*)ap;
      pa1 = *(const float4*)(ap + 4);
    }
    pbh = *(const sx8*)&Bth[brow + k0 + bk];
    pbl = *(const sx8*)&Btl[brow + k0 + bk];
  };

  const int w = t >> 6, l = t & 63, g = l >> 4, c = l & 15;
  const int wr = w >> 1, wc = w & 1;
  const int ra0 = (wr << 5) + c, ra1 = ra0 + 16;
  const int cb0 = (wc << 5) + c, cb1 = cb0 + 16;
  const int g8 = g << 3;

  fx4 acc00 = {0.f,0.f,0.f,0.f}, acc01 = acc00, acc10 = acc00, acc11 = acc00;

  LOADG(kbeg);
  for (int k0 = kbeg; k0 < kend; k0 += 32) {
    if constexpr (AMODE == 2) {
      *(sx8*)&Ah[ar][ak] = pah;
      *(sx8*)&Al[ar][ak] = pal;
    } else {
      sx4 AH0, AL0, AH1, AL1;
      AH0[0]=f2bf(pa0.x); AL0[0]=f2bf(pa0.x-bf2f(AH0[0]));
      AH0[1]=f2bf(pa0.y); AL0[1]=f2bf(pa0.y-bf2f(AH0[1]));
      AH0[2]=f2bf(pa0.z); AL0[2]=f2bf(pa0.z-bf2f(AH0[2]));
      AH0[3]=f2bf(pa0.w); AL0[3]=f2bf(pa0.w-bf2f(AH0[3]));
      AH1[0]=f2bf(pa1.x); AL1[0]=f2bf(pa1.x-bf2f(AH1[0]));
      AH1[1]=f2bf(pa1.y); AL1[1]=f2bf(pa1.y-bf2f(AH1[1]));
      AH1[2]=f2bf(pa1.z); AL1[2]=f2bf(pa1.z-bf2f(AH1[2]));
      AH1[3]=f2bf(pa1.w); AL1[3]=f2bf(pa1.w-bf2f(AH1[3]));
      *(sx4*)&Ah[ar][ak]     = AH0;  *(sx4*)&Ah[ar][ak + 4] = AH1;
      *(sx4*)&Al[ar][ak]     = AL0;  *(sx4*)&Al[ar][ak + 4] = AL1;
    }
    *(sx8*)&Bh[bc][bk] = pbh;      *(sx8*)&Bl[bc][bk] = pbl;
    __syncthreads();
    if (k0 + 32 < kend) LOADG(k0 + 32);

    sx8 a0h = *(const sx8*)&Ah[ra0][g8];
    sx8 a0l = *(const sx8*)&Al[ra0][g8];
    sx8 a1h = *(const sx8*)&Ah[ra1][g8];
    sx8 a1l = *(const sx8*)&Al[ra1][g8];
    sx8 b0h = *(const sx8*)&Bh[cb0][g8];
    sx8 b0l = *(const sx8*)&Bl[cb0][g8];
    sx8 b1h = *(const sx8*)&Bh[cb1][g8];
    sx8 b1l = *(const sx8*)&Bl[cb1][g8];

    acc00 = __builtin_amdgcn_mfma_f32_16x16x32_bf16(a0h, b0h, acc00, 0, 0, 0);
    acc01 = __builtin_amdgcn_mfma_f32_16x16x32_bf16(a0h, b1h, acc01, 0, 0, 0);
    acc10 = __builtin_amdgcn_mfma_f32_16x16x32_bf16(a1h, b0h, acc10, 0, 0, 0);
    acc11 = __builtin_amdgcn_mfma_f32_16x16x32_bf16(a1h, b1h, acc11, 0, 0, 0);
    acc00 = __builtin_amdgcn_mfma_f32_16x16x32_bf16(a0l, b0h, acc00, 0, 0, 0);
    acc01 = __builtin_amdgcn_mfma_f32_16x16x32_bf16(a0l, b1h, acc01, 0, 0, 0);
    acc10 = __builtin_amdgcn_mfma_f32_16x16x32_bf16(a1l, b0h, acc10, 0, 0, 0);
    acc11 = __builtin_amdgcn_mfma_f32_16x16x32_bf16(a1l, b1h, acc11, 0, 0, 0);
    acc00 = __builtin_amdgcn_mfma_f32_16x16x32_bf16(a0h, b0l, acc00, 0, 0, 0);
    acc01 = __builtin_amdgcn_mfma_f32_16x16x32_bf16(a0h, b1l, acc01, 0, 0, 0);
    acc10 = __builtin_amdgcn_mfma_f32_16x16x32_bf16(a1h, b0l, acc10, 0, 0, 0);
    acc11 = __builtin_amdgcn_mfma_f32_16x16x32_bf16(a1h, b1l, acc11, 0, 0, 0);
    __syncthreads();
  }

  const int col0 = bn + (wc << 5);
  const int row0 = bm + (wr << 5) + (g << 2);
  if constexpr (EPI == 0) {
    const float b0 = bias[col0 + c], b1 = bias[col0 + 16 + c];
#pragma unroll
    for (int i = 0; i < 4; ++i) {
      C[(size_t)(row0 + i) * N + col0 + c]           = acc00[i] + b0;
      C[(size_t)(row0 + i) * N + col0 + 16 + c]      = acc01[i] + b1;
      C[(size_t)(row0 + 16 + i) * N + col0 + c]      = acc10[i] + b0;
      C[(size_t)(row0 + 16 + i) * N + col0 + 16 + c] = acc11[i] + b1;
    }
  } else if constexpr (EPI == 1) {
    float* Cz = C + (size_t)blockIdx.z * M * N;
#pragma unroll
    for (int i = 0; i < 4; ++i) {
      Cz[(size_t)(row0 + i) * N + col0 + c]           = acc00[i];
      Cz[(size_t)(row0 + i) * N + col0 + 16 + c]      = acc01[i];
      Cz[(size_t)(row0 + 16 + i) * N + col0 + c]      = acc10[i];
      Cz[(size_t)(row0 + 16 + i) * N + col0 + 16 + c] = acc11[i];
    }
  } else if constexpr (EPI == 2) {
    const float b0 = bias[col0 + c], b1 = bias[col0 + 16 + c];
    auto emit = [&](int row, int n, float v) {
      int b = row >> 8, m = row & 255;
      short* dst = (n < 256) ? kout : vout;
      int nn = n & 255;
      int h = nn >> 5, d = nn & 31;
      dst[(size_t)(((b << 3) + h) * 256 + m) * 32 + d] = f2bf(v);
    };
#pragma unroll
    for (int i = 0; i < 4; ++i) {
      emit(row0 + i,      col0 + c,      acc00[i] + b0);
      emit(row0 + i,      col0 + 16 + c, acc01[i] + b1);
      emit(row0 + 16 + i, col0 + c,      acc10[i] + b0);
      emit(row0 + 16 + i, col0 + 16 + c, acc11[i] + b1);
    }
  } else {  // EPI == 3: q bf16, prescaled, [b*8+h][n][32]
    const float b0 = bias[col0 + c], b1 = bias[col0 + 16 + c];
    auto emitq = [&](int row, int n, float v) {
      int b = row >> 12, nn = row & 4095;
      int h = n >> 5, d = n & 31;
      kout[(size_t)(((b << 3) + h) * 4096 + nn) * 32 + d] = f2bf(v * QSCALE);
    };
#pragma unroll
    for (int i = 0; i < 4; ++i) {
      emitq(row0 + i,      col0 + c,      acc00[i] + b0);
      emitq(row0 + i,      col0 + 16 + c, acc01[i] + b1);
      emitq(row0 + 16 + i, col0 + c,      acc10[i] + b0);
      emitq(row0 + 16 + i, col0 + 16 + c, acc11[i] + b1);
    }
  }
}

// -------- fused K-split reduce + bias + LayerNorm: xs row per block --------
__global__ __launch_bounds__(256) void ln_reduce_kernel(
    const float* __restrict__ parts, const float* __restrict__ bias,
    const float* __restrict__ g, const float* __restrict__ bta,
    float* __restrict__ xs)
{
  const int row = blockIdx.x, t = threadIdx.x;
  const size_t MN = (size_t)4096 * 256;
  const size_t off = (size_t)row * CC + t;
  float v = parts[off] + parts[MN + off] + parts[2*MN + off] + parts[3*MN + off] + bias[t];
  float s = v, s2 = v * v;
#pragma unroll
  for (int offs = 32; offs; offs >>= 1) {
    s  += __shfl_xor(s,  offs, 64);
    s2 += __shfl_xor(s2, offs, 64);
  }
  __shared__ float red[8];
  const int w = t >> 6, lane = t & 63;
  if (lane == 0) { red[w] = s; red[4 + w] = s2; }
  __syncthreads();
  float ts  = red[0] + red[1] + red[2] + red[3];
  float ts2 = red[4] + red[5] + red[6] + red[7];
  float mu  = ts * (1.0f / 256.0f);
  float var = ts2 * (1.0f / 256.0f) - mu * mu;
  float o = (v - mu) * rsqrtf(var + 1e-6f) * g[t] + bta[t];
  xs[off] = o;
}

// ---------------- MFMA attention v3: bf16 Q in, split-bf16 O out ----------------
// 64 q-rows / block, 4 independent waves; K/V bf16 from global/LDS; softmax in
// log2 space fully in-register; O written as bf16 hi (over q buffer) + lo.
__global__ __launch_bounds__(256, 3) void attn_mfma3_kernel(
    short* __restrict__ qob, short* __restrict__ olo,
    const short* __restrict__ kbf, const short* __restrict__ vbf)
{
  __shared__ short Vt[32 * 264];       // V^T [d][m], stride 264
  __shared__ short Ps[4 * 16 * 264];   // per-wave P [16][264]

  const int tid = threadIdx.x;
  const int bid = blockIdx.x;
  const int nt = bid & 63, h = (bid >> 6) & 7, b = bid >> 9;
  const int n0 = nt << 6;
  const int bh = (b << 3) + h;
  const short* kb = kbf + (size_t)bh * 256 * 32;
  const short* vb = vbf + (size_t)bh * 256 * 32;

  // ---- stage V^T ----
  {
    sx8 v0 = *(const sx8*)&vb[tid * 32 + 0];
    sx8 v1 = *(const sx8*)&vb[tid * 32 + 8];
    sx8 v2 = *(const sx8*)&vb[tid * 32 + 16];
    sx8 v3 = *(const sx8*)&vb[tid * 32 + 24];
#pragma unroll
    for (int e = 0; e < 8; ++e) {
      Vt[(e)      * 264 + tid] = v0[e];
      Vt[(8 + e)  * 264 + tid] = v1[e];
      Vt[(16 + e) * 264 + tid] = v2[e];
      Vt[(24 + e) * 264 + tid] = v3[e];
    }
  }

  const int w = tid >> 6, l = tid & 63;
  const int g = l >> 4, c = l & 15;

  // ---- Q A-fragment: direct bf16 load (prescaled at q-proj) ----
  sx8 aq = *(const sx8*)&qob[((size_t)bh * 4096 + n0 + w * 16 + c) * 32 + (g << 3)];

  // ---- S = Q K^T ----
  fx4 acc[16];
#pragma unroll
  for (int j = 0; j < 16; ++j) {
    sx8 bk = *(const sx8*)&kb[(j * 16 + c) * 32 + (g << 3)];
    fx4 z = {0.f, 0.f, 0.f, 0.f};
    acc[j] = __builtin_amdgcn_mfma_f32_16x16x32_bf16(aq, bk, z, 0, 0, 0);
  }

  // ---- in-register softmax (lane: rows 4g+i, cols 16j+c) ----
  float mx[4], sm[4];
#pragma unroll
  for (int i = 0; i < 4; ++i) {
    float m0 = acc[0][i];
#pragma unroll
    for (int j = 1; j < 16; ++j) m0 = fmaxf(m0, acc[j][i]);
    m0 = fmaxf(m0, __shfl_xor(m0, 1, 64));
    m0 = fmaxf(m0, __shfl_xor(m0, 2, 64));
    m0 = fmaxf(m0, __shfl_xor(m0, 4, 64));
    m0 = fmaxf(m0, __shfl_xor(m0, 8, 64));
    mx[i] = m0;
  }
#pragma unroll
  for (int i = 0; i < 4; ++i) {
    float s0 = 0.f;
#pragma unroll
    for (int j = 0; j < 16; ++j) {
      float p = fexp2(acc[j][i] - mx[i]);
      acc[j][i] = p; s0 += p;
    }
    s0 += __shfl_xor(s0, 1, 64);
    s0 += __shfl_xor(s0, 2, 64);
    s0 += __shfl_xor(s0, 4, 64);
    s0 += __shfl_xor(s0, 8, 64);
    sm[i] = s0;
  }

  // ---- P (unnormalized bf16) -> LDS ----
  const int pbase = (w << 4) * 264;
#pragma unroll
  for (int j = 0; j < 16; ++j) {
#pragma unroll
    for (int i = 0; i < 4; ++i)
      Ps[pbase + ((g << 2) + i) * 264 + (j << 4) + c] = f2bf(acc[j][i]);
  }

  __syncthreads();

  // ---- O = P V ----
  fx4 o0 = {0.f,0.f,0.f,0.f}, o1 = {0.f,0.f,0.f,0.f};
#pragma unroll
  for (int s = 0; s < 8; ++s) {
    sx8 ap  = *(const sx8*)&Ps[pbase + c * 264 + (s << 5) + (g << 3)];
    sx8 bv0 = *(const sx8*)&Vt[(c)      * 264 + (s << 5) + (g << 3)];
    sx8 bv1 = *(const sx8*)&Vt[(16 + c) * 264 + (s << 5) + (g << 3)];
    o0 = __builtin_amdgcn_mfma_f32_16x16x32_bf16(ap, bv0, o0, 0, 0, 0);
    o1 = __builtin_amdgcn_mfma_f32_16x16x32_bf16(ap, bv1, o1, 0, 0, 0);
  }

  // ---- normalize, split to bf16 hi/lo, write [b*8+h][n][32] ----
#pragma unroll
  for (int i = 0; i < 4; ++i) {
    float inv = frcp(sm[i]);
    int n = n0 + w * 16 + (g << 2) + i;
    size_t base = ((size_t)bh * 4096 + n) * 32;
    float v0 = o0[i] * inv, v1 = o1[i] * inv;
    short h0 = f2bf(v0), h1 = f2bf(v1);
    qob[base + c]      = h0;  olo[base + c]      = f2bf(v0 - bf2f(h0));
    qob[base + 16 + c] = h1;  olo[base + 16 + c] = f2bf(v1 - bf2f(h1));
  }
}

extern "C" void kernel_launch(void* const* d_in, const int* in_sizes, int n_in,
                              void* d_out, int out_size, void* d_ws, size_t ws_size,
                              hipStream_t stream) {
  const float* x      = (const float*)d_in[0];
  const float* q_w    = (const float*)d_in[1];
  const float* q_b    = (const float*)d_in[2];
  const float* kv_w   = (const float*)d_in[3];
  const float* kv_b   = (const float*)d_in[4];
  const float* sr_w   = (const float*)d_in[5];
  const float* sr_b   = (const float*)d_in[6];
  const float* norm_g = (const float*)d_in[7];
  const float* norm_b = (const float*)d_in[8];
  const float* proj_w = (const float*)d_in[9];
  const float* proj_b = (const float*)d_in[10];
  float* out = (float*)d_out;

  float* xsbuf = (float*)d_ws;                     // 1M f (4 MB)
  short* qbf   = (short*)(xsbuf + 1048576);        // 16.7M s (32 MB): q, then O-hi
  float* partf = (float*)qbf;                      // 4M f (16 MB) alias, dead before q-proj
  short* olo   = qbf + 16777216;                   // 16.7M s (32 MB): O-lo
  short* kbf   = olo + 16777216;                   // 2M s (4 MB)
  short* vbf   = kbf + 2097152;                    // 2M s (4 MB)
  short* qwt_h  = vbf + 2097152;
  short* qwt_l  = qwt_h + 65536;
  short* kvwt_h = qwt_l + 65536;
  short* kvwt_l = kvwt_h + 131072;
  short* pwt_h  = kvwt_l + 131072;
  short* pwt_l  = pwt_h + 65536;
  short* swt_h  = pwt_l + 65536;
  short* swt_l  = swt_h + 1048576;

  dim3 blk(256);

  wsplit_kernel<<<dim3(CC/64, CC/64), blk, 0, stream>>>(q_w, qwt_h, qwt_l, CC, CC);
  wsplit_kernel<<<dim3(2*CC/64, CC/64), blk, 0, stream>>>(kv_w, kvwt_h, kvwt_l, CC, 2*CC);
  wsplit_kernel<<<dim3(CC/64, CC/64), blk, 0, stream>>>(proj_w, pwt_h, pwt_l, CC, CC);
  wsplit_kernel<<<dim3(CC/64, 4096/64), blk, 0, stream>>>(sr_w, swt_h, swt_l, 4096, CC);

  // conv (gathered GEMM, K=4096) with K-split x4 -> f32 partials
  gemm_split_kernel<1,1><<<dim3(CC/64, (B_*MM)/64, 4), blk, 0, stream>>>(
      x, nullptr, swt_h, swt_l, sr_b, partf, nullptr, nullptr, B_*MM, CC, 4096);

  // fused reduce + bias + LayerNorm
  ln_reduce_kernel<<<B_ * MM, blk, 0, stream>>>(partf, sr_b, norm_g, norm_b, xsbuf);

  // kv = xs @ kv_w + kv_b -> bf16 K/V [b*8+h][m][32]
  gemm_split_kernel<0,2><<<dim3((2*CC)/64, (B_*MM)/64, 1), blk, 0, stream>>>(
      xsbuf, nullptr, kvwt_h, kvwt_l, kv_b, nullptr, kbf, vbf, B_*MM, 2*CC, CC);

  // q = x @ q_w + q_b -> bf16 prescaled [b*8+h][n][32]  (after partf is dead)
  gemm_split_kernel<0,3><<<dim3(CC/64, (B_*NN)/64, 1), blk, 0, stream>>>(
      x, nullptr, qwt_h, qwt_l, q_b, nullptr, qbf, nullptr, B_*NN, CC, CC);

  // attention: reads qbf, writes O-hi over qbf + O-lo
  attn_mfma3_kernel<<<B_ * NH * (NN / 64), blk, 0, stream>>>(qbf, olo, kbf, vbf);

  // out = O @ proj_w + proj_b  (A pre-split bf16 head-major)
  gemm_split_kernel<2,0><<<dim3(CC/64, (B_*NN)/64, 1), blk, 0, stream>>>(
      qbf, olo, pwt_h, pwt_l, proj_b, out, nullptr, nullptr, B_*NN, CC, CC);
}